// Round 1
// baseline (631.903 us; speedup 1.0000x reference)
//
#include <hip/hip_runtime.h>
#include <stdint.h>

#define DDIM 512
#define BROWS 65536
#define EPSF 1e-15f
#define MAXNF 0.996f
#define SQRT_EPSF 3.1622776e-8f
#define ATANH_CLIP 0.99999988f

typedef __bf16 bf16x8 __attribute__((ext_vector_type(8)));
typedef float f32x4 __attribute__((ext_vector_type(4)));

__device__ __forceinline__ unsigned short f2bf(float f) {
    union { float f; uint32_t u; } c; c.f = f;
    uint32_t u = c.u;
    u += 0x7fffu + ((u >> 16) & 1u);
    return (unsigned short)(u >> 16);
}

__device__ __forceinline__ float wred(float v) {
    v += __shfl_xor(v, 1);
    v += __shfl_xor(v, 2);
    v += __shfl_xor(v, 4);
    v += __shfl_xor(v, 8);
    v += __shfl_xor(v, 16);
    v += __shfl_xor(v, 32);
    return v;
}

__device__ __forceinline__ float fast_asinh(float t) {
    return __logf(t + sqrtf(fmaf(t, t, 1.0f)));
}
__device__ __forceinline__ float fast_sinh(float v) {
    float q = __expf(v);
    return 0.5f * (q - __builtin_amdgcn_rcpf(q));
}

// ---------------- prep: zn, cosh/sinh(2b), transposed bf16 z_unit ----------------
__global__ void prep_kernel(const float* __restrict__ z, const float* __restrict__ bias,
                            float* __restrict__ znf, float* __restrict__ chv,
                            float* __restrict__ shv, unsigned short* __restrict__ zT) {
    int j = blockIdx.x;   // out column
    int l = threadIdx.x;  // 0..63
    float zv[8];
    float s = 0.f;
#pragma unroll
    for (int t = 0; t < 8; ++t) {
        float v = z[(size_t)(t * 64 + l) * DDIM + j];
        zv[t] = v;
        s = fmaf(v, v, s);
    }
    s = wred(s);
    float zn = sqrtf(fmaxf(s, EPSF));
    float inv = 1.0f / zn;
#pragma unroll
    for (int t = 0; t < 8; ++t)
        zT[(size_t)j * DDIM + t * 64 + l] = f2bf(zv[t] * inv);
    if (l == 0) {
        znf[j] = zn;
        float tr = 2.0f * bias[j];
        chv[j] = coshf(tr);
        shv[j] = sinhf(tr);
    }
}

// ---------------- fused main kernel ----------------
// 64 rows/block, 512 threads (8 waves). Wave w: n-range [w*64, w*64+64), all 4 m-subtiles.
__global__ __launch_bounds__(512, 2) void hpd_main(
    const float* __restrict__ Xc, const float* __restrict__ Xp,
    const float* __restrict__ znf, const float* __restrict__ chv, const float* __restrict__ shv,
    const unsigned short* __restrict__ zT,
    const float* __restrict__ alpha_p, const float* __restrict__ step_p,
    float* __restrict__ out)
{
    __shared__ __align__(16) unsigned char smem[98816];
    // [0,65536): e bf16 [64][512] swizzled (reused as 32x512 f32 stage in epilogue)
    // [65536,98304): z tile bf16 [32k x 512n] swizzled
    // [98304,98560): per-row cx2 ; [98560,98816): per-row dcc
    unsigned char* zbuf = smem + 65536;
    float* scx2 = (float*)(smem + 98304);
    float* sdcc = (float*)(smem + 98560);

    const int t = threadIdx.x;
    const int w = t >> 6;
    const int l = t & 63;
    const int l15 = l & 15;
    const int quad = l >> 4;
    const int r0 = blockIdx.x * 64;
    const size_t BDo = (size_t)BROWS * DDIM;

    float a_sig = 1.0f / (1.0f + __expf(-alpha_p[0]));
    float step_sig = 1.0f / (1.0f + __expf(-step_p[0]));

    // ---------------- Phase A: dots, bt, e ----------------
    float xcreg[8][8];
#pragma unroll
    for (int idx = 0; idx < 8; ++idx) {
        int row = (idx < 4) ? (w * 4 + idx) : (32 + w * 4 + (idx - 4));
        const float4* pc = (const float4*)(Xc + (size_t)(r0 + row) * DDIM + l * 8);
        const float4* pp = (const float4*)(Xp + (size_t)(r0 + row) * DDIM + l * 8);
        float4 c0 = pc[0], c1 = pc[1];
        float4 p0 = pp[0], p1 = pp[1];
        float xcv[8] = {c0.x, c0.y, c0.z, c0.w, c1.x, c1.y, c1.z, c1.w};
        float xpv[8] = {p0.x, p0.y, p0.z, p0.w, p1.x, p1.y, p1.z, p1.w};
        float dcc = 0.f, dpp = 0.f, dpc = 0.f;
#pragma unroll
        for (int j = 0; j < 8; ++j) {
            dcc = fmaf(xcv[j], xcv[j], dcc);
            dpp = fmaf(xpv[j], xpv[j], dpp);
            dpc = fmaf(xpv[j], xcv[j], dpc);
        }
        dcc = wred(dcc); dpp = wred(dpp); dpc = wred(dpc);
        // sub = mobius_add(-p, x) = (Ca*p + Cb*x)/den
        float Ca = -(1.0f - 2.0f * dpc + dcc);
        float Cb = 1.0f - dpp;
        float den = fmaxf(1.0f - 2.0f * dpc + dpp * dcc, EPSF);
        float ssub = (Ca * Ca * dpp + 2.0f * Ca * Cb * dpc + Cb * Cb * dcc) / (den * den);
        float sn = sqrtf(fmaxf(ssub, EPSF));
        float tol = fmaxf(1.0f - dpp, EPSF);              // 2/lam
        float art = atanhf(fminf(sn, ATANH_CLIP));
        float sbt = tol * art / sn;                        // bt = sbt*sub
        float un = fmaxf(tol * art, SQRT_EPSF);            // ||bt||
        float te = tanhf(un);
        float se = te / un * sbt;                          // e = se*sub
        float cep = se * Ca / den;
        float cex = se * Cb / den;
        if (l == 0) { scx2[row] = te * te; sdcc[row] = dcc; }
        unsigned short e8[8];
#pragma unroll
        for (int j = 0; j < 8; ++j) {
            e8[j] = f2bf(fmaf(cex, xcv[j], cep * xpv[j]));
            xcreg[idx][j] = xcv[j];
        }
        uint32_t u0 = (uint32_t)e8[0] | ((uint32_t)e8[1] << 16);
        uint32_t u1 = (uint32_t)e8[2] | ((uint32_t)e8[3] << 16);
        uint32_t u2 = (uint32_t)e8[4] | ((uint32_t)e8[5] << 16);
        uint32_t u3 = (uint32_t)e8[6] | ((uint32_t)e8[7] << 16);
        uint32_t off = row * 1024 + ((l ^ (row & 7)) * 16);
        *(uint4*)(smem + off) = make_uint4(u0, u1, u2, u3);
    }
    __syncthreads();

    // ---------------- K-loop: inner = e @ z_unit ----------------
    f32x4 acc[4][4];
#pragma unroll
    for (int m = 0; m < 4; ++m)
#pragma unroll
        for (int j = 0; j < 4; ++j)
            acc[m][j] = (f32x4){0.f, 0.f, 0.f, 0.f};

#pragma unroll 1
    for (int ks = 0; ks < 16; ++ks) {
        // stage z tile [k=32][n=512] from zT[n][k] (bf16), swizzled layout
#pragma unroll
        for (int j = 0; j < 4; ++j) {
            int q = j * 512 + t;
            int n = q >> 2, c = q & 3;
            uint4 d = *(const uint4*)((const unsigned char*)zT + n * 1024 + ks * 64 + c * 16);
            int g = n >> 2;
            uint32_t off = g * 256 + (n & 3) * 16 + (((c + g) & 3) * 64);
            *(uint4*)(zbuf + off) = d;
        }
        __syncthreads();
        bf16x8 af[4], bfr[4];
#pragma unroll
        for (int m = 0; m < 4; ++m) {
            int row = m * 16 + l15;
            uint32_t off = row * 1024 + (((ks * 4 + quad) ^ (row & 7)) * 16);
            af[m] = *(const bf16x8*)(smem + off);
        }
#pragma unroll
        for (int j = 0; j < 4; ++j) {
            int n = w * 64 + j * 16 + l15;
            uint32_t off = (n >> 2) * 256 + (n & 3) * 16 + (((quad + (n >> 2)) & 3) * 64);
            bfr[j] = *(const bf16x8*)(zbuf + off);
        }
#pragma unroll
        for (int m = 0; m < 4; ++m)
#pragma unroll
            for (int j = 0; j < 4; ++j)
                acc[m][j] = __builtin_amdgcn_mfma_f32_16x16x32_bf16(af[m], bfr[j], acc[m][j], 0, 0, 0);
        __syncthreads();
    }

    // ---------------- Epilogue: two 32-row halves through reused LDS ----------------
    float* stage = (float*)smem;  // [32][512] f32
#pragma unroll
    for (int h = 0; h < 2; ++h) {
        __syncthreads();
#pragma unroll
        for (int mm = 0; mm < 2; ++mm) {
            int m = 2 * h + mm;
#pragma unroll
            for (int j = 0; j < 4; ++j) {
#pragma unroll
                for (int r = 0; r < 4; ++r) {
                    int rowl = mm * 16 + quad * 4 + r;
                    int n = w * 64 + j * 16 + l15;
                    stage[rowl * 512 + n] = acc[m][j][r];
                }
            }
        }
        __syncthreads();
#pragma unroll
        for (int i = 0; i < 4; ++i) {
            int rowl = w * 4 + i;         // local row in half
            int row = h * 32 + rowl;      // 0..63
            int idx = h * 4 + i;
            int grow = r0 + row;
            float4 in0 = *(const float4*)(stage + rowl * 512 + l * 8);
            float4 in1 = *(const float4*)(stage + rowl * 512 + l * 8 + 4);
            float inr[8] = {in0.x, in0.y, in0.z, in0.w, in1.x, in1.y, in1.z, in1.w};
            float4 zn0 = *(const float4*)(znf + l * 8);
            float4 zn1 = *(const float4*)(znf + l * 8 + 4);
            float4 ch0 = *(const float4*)(chv + l * 8);
            float4 ch1 = *(const float4*)(chv + l * 8 + 4);
            float4 sh0 = *(const float4*)(shv + l * 8);
            float4 sh1 = *(const float4*)(shv + l * 8 + 4);
            float znv[8] = {zn0.x, zn0.y, zn0.z, zn0.w, zn1.x, zn1.y, zn1.z, zn1.w};
            float chvv[8] = {ch0.x, ch0.y, ch0.z, ch0.w, ch1.x, ch1.y, ch1.z, ch1.w};
            float shvv[8] = {sh0.x, sh0.y, sh0.z, sh0.w, sh1.x, sh1.y, sh1.z, sh1.w};
            float cx2 = scx2[row], dcc = sdcc[row];
            float inv1m = 1.0f / fmaxf(1.0f - cx2, EPSF);
            float opc = 1.0f + cx2;
            float wv[8];
            float sw = 0.f, cw = 0.f;
#pragma unroll
            for (int j = 0; j < 8; ++j) {
                float arg = (2.0f * inr[j] * chvv[j] - opc * shvv[j]) * inv1m;
                float v = 2.0f * znv[j] * fast_asinh(arg);
                wv[j] = fast_sinh(v);
                sw = fmaf(wv[j], wv[j], sw);
                cw = fmaf(xcreg[idx][j], wv[j], cw);
            }
            sw = wred(sw); cw = wred(cw);
            // scalar chain over basis (x, w)
            float is = 1.0f / (1.0f + sqrtf(1.0f + sw));       // fc = is*w
            float nfc = sqrtf(fmaxf(sw * is * is, EPSF));
            float artf = atanhf(fminf(nfc, ATANH_CLIP));
            float un2 = fmaxf(step_sig * artf, SQRT_EPSF);
            float g = tanhf(un2 / fmaxf(1.0f - dcc, EPSF));
            float by = g * is / nfc;                           // y = by*w
            float xy = by * cw;
            float y2 = by * by * sw;
            float P = 1.0f + 2.0f * xy + y2;
            float den2 = fmaxf(1.0f + 2.0f * xy + dcc * y2, EPSF);
            float a1 = P / den2;
            float b1 = (1.0f - dcc) * by / den2;               // xur = a1*x + b1*w
            float s2u = a1 * a1 * dcc + 2.0f * a1 * b1 * cw + b1 * b1 * sw;
            float nxu = sqrtf(fmaxf(s2u, EPSF));
            float pj = (nxu > MAXNF) ? (MAXNF / nxu) : 1.0f;
            a1 *= pj; b1 *= pj;
            float nxu2 = fminf(nxu, MAXNF);
            // xc projection
            float nx = sqrtf(fmaxf(dcc, EPSF));
            float sxc = (nx > MAXNF) ? (MAXNF / nx) : 1.0f;
            float nxc = fminf(nx, MAXNF);
            float A1 = tanhf(a_sig * atanhf(fminf(nxc, ATANH_CLIP))) / nxc * sxc;  // m1 = A1*x
            float t2s = tanhf((1.0f - a_sig) * atanhf(fminf(nxu2, ATANH_CLIP)));
            float sm2 = t2s / fmaxf(nxu2, SQRT_EPSF);
            float A2 = sm2 * a1, B2 = sm2 * b1;                // m2 = A2*x + B2*w
            float x2m = A1 * A1 * dcc;
            float y2m = A2 * A2 * dcc + 2.0f * A2 * B2 * cw + B2 * B2 * sw;
            float xym = A1 * (A2 * dcc + B2 * cw);
            float num1 = 1.0f + 2.0f * xym + y2m;
            float num2 = 1.0f - x2m;
            float den3 = fmaxf(1.0f + 2.0f * xym + x2m * y2m, EPSF);
            float an = (num1 * A1 + num2 * A2) / den3;
            float bn = (num2 * B2) / den3;
            float s2n = an * an * dcc + 2.0f * an * bn * cw + bn * bn * sw;
            float nn = sqrtf(fmaxf(s2n, EPSF));
            float pj2 = (nn > MAXNF) ? (MAXNF / nn) : 1.0f;
            an *= pj2; bn *= pj2;
            // outputs
            float o0[8], o1[8];
#pragma unroll
            for (int j = 0; j < 8; ++j) {
                o0[j] = fmaf(an, xcreg[idx][j], bn * wv[j]);
                o1[j] = sxc * xcreg[idx][j];
            }
            float* p0 = out + (size_t)grow * DDIM + l * 8;
            float* p1 = out + BDo + (size_t)grow * DDIM + l * 8;
            *(float4*)(p0) = make_float4(o0[0], o0[1], o0[2], o0[3]);
            *(float4*)(p0 + 4) = make_float4(o0[4], o0[5], o0[6], o0[7]);
            *(float4*)(p1) = make_float4(o1[0], o1[1], o1[2], o1[3]);
            *(float4*)(p1 + 4) = make_float4(o1[4], o1[5], o1[6], o1[7]);
        }
    }
}

extern "C" void kernel_launch(void* const* d_in, const int* in_sizes, int n_in,
                              void* d_out, int out_size, void* d_ws, size_t ws_size,
                              hipStream_t stream) {
    const float* xc = (const float*)d_in[0];
    const float* xp = (const float*)d_in[1];
    const float* z = (const float*)d_in[2];
    const float* bias = (const float*)d_in[3];
    const float* alpha = (const float*)d_in[4];
    const float* stepsz = (const float*)d_in[5];
    float* out = (float*)d_out;

    float* znf = (float*)d_ws;            // 512 f32
    float* chv = znf + 512;               // 512 f32
    float* shv = znf + 1024;              // 512 f32
    unsigned short* zT = (unsigned short*)(znf + 1536);  // 512x512 bf16 (transposed z_unit)

    prep_kernel<<<512, 64, 0, stream>>>(z, bias, znf, chv, shv, zT);
    hpd_main<<<BROWS / 64, 512, 0, stream>>>(xc, xp, znf, chv, shv, zT, alpha, stepsz, out);
}

// Round 2
// 569.160 us; speedup vs baseline: 1.1102x; 1.1102x over previous
//
#include <hip/hip_runtime.h>
#include <stdint.h>

#define DDIM 512
#define BROWS 65536
#define EPSF 1e-15f
#define MAXNF 0.996f
#define SQRT_EPSF 3.1622776e-8f
#define ATANH_CLIP 0.99999988f

typedef __bf16 bf16x8 __attribute__((ext_vector_type(8)));
typedef float f32x4 __attribute__((ext_vector_type(4)));

__device__ __forceinline__ unsigned short f2bf(float f) {
    union { float f; uint32_t u; } c; c.f = f;
    uint32_t u = c.u;
    u += 0x7fffu + ((u >> 16) & 1u);
    return (unsigned short)(u >> 16);
}

__device__ __forceinline__ float rcpf(float x) { return __builtin_amdgcn_rcpf(x); }

__device__ __forceinline__ float wred(float v) {
    v += __shfl_xor(v, 1);
    v += __shfl_xor(v, 2);
    v += __shfl_xor(v, 4);
    v += __shfl_xor(v, 8);
    v += __shfl_xor(v, 16);
    v += __shfl_xor(v, 32);
    return v;
}

// x >= 0
__device__ __forceinline__ float fast_tanh_pos(float x) {
    float t = __expf(-2.0f * x);
    return (1.0f - t) * rcpf(1.0f + t);
}
// 0 <= x < 1
__device__ __forceinline__ float fast_atanh_pos(float x) {
    return 0.5f * __logf((1.0f + x) * rcpf(1.0f - x));
}
__device__ __forceinline__ float fast_asinh(float t) {
    float a = fabsf(t);
    float r = __logf(a + sqrtf(fmaf(a, a, 1.0f)));
    return copysignf(r, t);
}
__device__ __forceinline__ float fast_sinh(float v) {
    float q = __expf(v);
    return 0.5f * (q - rcpf(q));
}

// ---------------- prep: zn, cosh/sinh(2b), transposed bf16 z_unit ----------------
__global__ void prep_kernel(const float* __restrict__ z, const float* __restrict__ bias,
                            float* __restrict__ znf, float* __restrict__ chv,
                            float* __restrict__ shv, unsigned short* __restrict__ zT) {
    int j = blockIdx.x;   // out column
    int l = threadIdx.x;  // 0..63
    float zv[8];
    float s = 0.f;
#pragma unroll
    for (int t = 0; t < 8; ++t) {
        float v = z[(size_t)(t * 64 + l) * DDIM + j];
        zv[t] = v;
        s = fmaf(v, v, s);
    }
    s = wred(s);
    float zn = sqrtf(fmaxf(s, EPSF));
    float inv = 1.0f / zn;
#pragma unroll
    for (int t = 0; t < 8; ++t)
        zT[(size_t)j * DDIM + t * 64 + l] = f2bf(zv[t] * inv);
    if (l == 0) {
        znf[j] = zn;
        float tr = 2.0f * bias[j];
        chv[j] = coshf(tr);
        shv[j] = sinhf(tr);
    }
}

// ---------------- fused main kernel ----------------
// 64 rows/block, 512 threads (8 waves), 2 blocks/CU.
__global__ __launch_bounds__(512, 4) void hpd_main(
    const float* __restrict__ Xc, const float* __restrict__ Xp,
    const float* __restrict__ znf, const float* __restrict__ chv, const float* __restrict__ shv,
    const unsigned short* __restrict__ zT,
    const float* __restrict__ alpha_p, const float* __restrict__ step_p,
    float* __restrict__ out)
{
    __shared__ __align__(16) unsigned char smem[70656];
    // [0,65536): e bf16 [64][512] XOR-swizzled (MFMA A staging)
    float* cx2s = (float*)(smem + 65536);   // 64
    float* dccs = (float*)(smem + 65792);   // 64
    float* swp  = (float*)(smem + 66048);   // [64][8]
    float* cwp  = (float*)(smem + 68096);   // [64][8]
    float* ans  = (float*)(smem + 70144);   // 64
    float* bns  = (float*)(smem + 70400);   // 64

    const int t = threadIdx.x;
    const int w = t >> 6;
    const int l = t & 63;
    const int l15 = l & 15;
    const int quad = l >> 4;
    const int r0 = blockIdx.x * 64;

    float a_sig = rcpf(1.0f + __expf(-alpha_p[0]));
    float step_sig = rcpf(1.0f + __expf(-step_p[0]));

    float* out1 = out + (size_t)BROWS * DDIM;

    // ---------------- Phase A: dots, bt, e, and xc output ----------------
#pragma unroll
    for (int idx = 0; idx < 8; ++idx) {
        int row = w * 4 + (idx & 3) + ((idx >> 2) << 5);
        const float* pc = Xc + (size_t)(r0 + row) * DDIM + l * 8;
        const float* pp = Xp + (size_t)(r0 + row) * DDIM + l * 8;
        float4 c0 = *(const float4*)pc; float4 c1 = *(const float4*)(pc + 4);
        float4 p0 = *(const float4*)pp; float4 p1 = *(const float4*)(pp + 4);
        float xcv[8] = {c0.x, c0.y, c0.z, c0.w, c1.x, c1.y, c1.z, c1.w};
        float xpv[8] = {p0.x, p0.y, p0.z, p0.w, p1.x, p1.y, p1.z, p1.w};
        float dcc = 0.f, dpp = 0.f, dpc = 0.f;
#pragma unroll
        for (int j = 0; j < 8; ++j) {
            dcc = fmaf(xcv[j], xcv[j], dcc);
            dpp = fmaf(xpv[j], xpv[j], dpp);
            dpc = fmaf(xpv[j], xcv[j], dpc);
        }
        dcc = wred(dcc); dpp = wred(dpp); dpc = wred(dpc);
        // sub = mobius_add(-p, x) = (Ca*p + Cb*x)/den
        float Ca = -(1.0f - 2.0f * dpc + dcc);
        float Cb = 1.0f - dpp;
        float den = fmaxf(1.0f - 2.0f * dpc + dpp * dcc, EPSF);
        float rden = rcpf(den);
        float ssub = (Ca * Ca * dpp + 2.0f * Ca * Cb * dpc + Cb * Cb * dcc) * rden * rden;
        float sn = sqrtf(fmaxf(ssub, EPSF));
        float tol = fmaxf(1.0f - dpp, EPSF);              // 2/lam
        float art = fast_atanh_pos(fminf(sn, ATANH_CLIP));
        float sbt = tol * art * rcpf(sn);                  // bt = sbt*sub
        float un = fmaxf(tol * art, SQRT_EPSF);            // ||bt||
        float te = fast_tanh_pos(un);
        float se = te * rcpf(un) * sbt;                    // e = se*sub
        float cep = se * Ca * rden;
        float cex = se * Cb * rden;
        if (l == 0) { cx2s[row] = te * te; dccs[row] = dcc; }
        // xc = projx(x_current)  -> output 1, done right here
        float nx = sqrtf(fmaxf(dcc, EPSF));
        float sxc = (nx > MAXNF) ? (MAXNF * rcpf(nx)) : 1.0f;
        float* po1 = out1 + (size_t)(r0 + row) * DDIM + l * 8;
        *(float4*)po1 = make_float4(sxc * xcv[0], sxc * xcv[1], sxc * xcv[2], sxc * xcv[3]);
        *(float4*)(po1 + 4) = make_float4(sxc * xcv[4], sxc * xcv[5], sxc * xcv[6], sxc * xcv[7]);
        unsigned short e8[8];
#pragma unroll
        for (int j = 0; j < 8; ++j)
            e8[j] = f2bf(fmaf(cex, xcv[j], cep * xpv[j]));
        uint32_t u0 = (uint32_t)e8[0] | ((uint32_t)e8[1] << 16);
        uint32_t u1 = (uint32_t)e8[2] | ((uint32_t)e8[3] << 16);
        uint32_t u2 = (uint32_t)e8[4] | ((uint32_t)e8[5] << 16);
        uint32_t u3 = (uint32_t)e8[6] | ((uint32_t)e8[7] << 16);
        uint32_t off = row * 1024 + ((l ^ (row & 7)) * 16);
        *(uint4*)(smem + off) = make_uint4(u0, u1, u2, u3);
    }
    __syncthreads();

    // ---------------- K-loop: inner = e @ z_unit (B direct from L2, no barriers) ----------------
    f32x4 acc[4][4];
#pragma unroll
    for (int m = 0; m < 4; ++m)
#pragma unroll
        for (int j = 0; j < 4; ++j)
            acc[m][j] = (f32x4){0.f, 0.f, 0.f, 0.f};

    const unsigned short* zbase = zT + (size_t)(w * 64 + l15) * DDIM + quad * 8;
#pragma unroll 1
    for (int ks = 0; ks < 16; ++ks) {
        bf16x8 af[4], bfr[4];
#pragma unroll
        for (int j = 0; j < 4; ++j)
            bfr[j] = *(const bf16x8*)(zbase + (size_t)j * 16 * DDIM + ks * 32);
#pragma unroll
        for (int m = 0; m < 4; ++m) {
            int row = m * 16 + l15;
            af[m] = *(const bf16x8*)(smem + row * 1024 + (((ks * 4 + quad) ^ (row & 7)) * 16));
        }
#pragma unroll
        for (int m = 0; m < 4; ++m)
#pragma unroll
            for (int j = 0; j < 4; ++j)
                acc[m][j] = __builtin_amdgcn_mfma_f32_16x16x32_bf16(af[m], bfr[j], acc[m][j], 0, 0, 0);
    }

    // ---------------- Epilogue: in-register C-layout ----------------
    // C layout: row = m*16 + quad*4 + r, col = w*64 + j*16 + l15
    float znv[4], chc[4], shc[4];
#pragma unroll
    for (int j = 0; j < 4; ++j) {
        int col = w * 64 + j * 16 + l15;
        znv[j] = znf[col]; chc[j] = chv[col]; shc[j] = shv[col];
    }
    const float* xb = Xc + (size_t)r0 * DDIM + w * 64 + l15;

#pragma unroll
    for (int m = 0; m < 4; ++m) {
        int rbase = m * 16 + quad * 4;
        float inv1m[4], opc[4];
#pragma unroll
        for (int r = 0; r < 4; ++r) {
            float c2 = cx2s[rbase + r];
            inv1m[r] = rcpf(fmaxf(1.0f - c2, EPSF));
            opc[r] = 1.0f + c2;
        }
        float swr[4] = {0.f, 0.f, 0.f, 0.f}, cwr[4] = {0.f, 0.f, 0.f, 0.f};
#pragma unroll
        for (int j = 0; j < 4; ++j) {
#pragma unroll
            for (int r = 0; r < 4; ++r) {
                float inner = acc[m][j][r];
                float arg = fmaf(2.0f * inner, chc[j], -opc[r] * shc[j]) * inv1m[r];
                float v = 2.0f * znv[j] * fast_asinh(arg);
                float wv = fast_sinh(v);
                acc[m][j][r] = wv;   // overwrite accumulator with w
                float xv = xb[(size_t)(rbase + r) * DDIM + j * 16];
                swr[r] = fmaf(wv, wv, swr[r]);
                cwr[r] = fmaf(xv, wv, cwr[r]);
            }
        }
#pragma unroll
        for (int r = 0; r < 4; ++r) {
            float s = swr[r], c = cwr[r];
            s += __shfl_xor(s, 1); s += __shfl_xor(s, 2); s += __shfl_xor(s, 4); s += __shfl_xor(s, 8);
            c += __shfl_xor(c, 1); c += __shfl_xor(c, 2); c += __shfl_xor(c, 4); c += __shfl_xor(c, 8);
            if (l15 == 0) { swp[(rbase + r) * 8 + w] = s; cwp[(rbase + r) * 8 + w] = c; }
        }
    }
    __syncthreads();

    // per-row scalar chain on 64 threads
    if (t < 64) {
        int row = t;
        float4 s0 = *(const float4*)(swp + row * 8);
        float4 s1 = *(const float4*)(swp + row * 8 + 4);
        float sw = ((s0.x + s0.y) + (s0.z + s0.w)) + ((s1.x + s1.y) + (s1.z + s1.w));
        float4 q0 = *(const float4*)(cwp + row * 8);
        float4 q1 = *(const float4*)(cwp + row * 8 + 4);
        float cw = ((q0.x + q0.y) + (q0.z + q0.w)) + ((q1.x + q1.y) + (q1.z + q1.w));
        float dcc = dccs[row];
        float is = 1.0f / (1.0f + sqrtf(1.0f + sw));       // fc = is*w
        float nfc = sqrtf(fmaxf(sw * is * is, EPSF));
        float artf = fast_atanh_pos(fminf(nfc, ATANH_CLIP));
        float un2 = fmaxf(step_sig * artf, SQRT_EPSF);
        float g = fast_tanh_pos(un2 / fmaxf(1.0f - dcc, EPSF));
        float by = g * is / nfc;                           // y = by*w
        float xy = by * cw;
        float y2 = by * by * sw;
        float P = 1.0f + 2.0f * xy + y2;
        float den2 = fmaxf(1.0f + 2.0f * xy + dcc * y2, EPSF);
        float a1 = P / den2;
        float b1 = (1.0f - dcc) * by / den2;               // xur = a1*x + b1*w
        float s2u = a1 * a1 * dcc + 2.0f * a1 * b1 * cw + b1 * b1 * sw;
        float nxu = sqrtf(fmaxf(s2u, EPSF));
        float pj = (nxu > MAXNF) ? (MAXNF / nxu) : 1.0f;
        a1 *= pj; b1 *= pj;
        float nxu2 = fminf(nxu, MAXNF);
        float nx = sqrtf(fmaxf(dcc, EPSF));
        float sxc = (nx > MAXNF) ? (MAXNF / nx) : 1.0f;
        float nxc = fminf(nx, MAXNF);
        float A1 = fast_tanh_pos(a_sig * fast_atanh_pos(fminf(nxc, ATANH_CLIP))) / nxc * sxc;
        float t2s = fast_tanh_pos((1.0f - a_sig) * fast_atanh_pos(fminf(nxu2, ATANH_CLIP)));
        float sm2 = t2s / fmaxf(nxu2, SQRT_EPSF);
        float A2 = sm2 * a1, B2 = sm2 * b1;                // m2 = A2*x + B2*w
        float x2m = A1 * A1 * dcc;
        float y2m = A2 * A2 * dcc + 2.0f * A2 * B2 * cw + B2 * B2 * sw;
        float xym = A1 * (A2 * dcc + B2 * cw);
        float num1 = 1.0f + 2.0f * xym + y2m;
        float num2 = 1.0f - x2m;
        float den3 = fmaxf(1.0f + 2.0f * xym + x2m * y2m, EPSF);
        float an = (num1 * A1 + num2 * A2) / den3;
        float bn = (num2 * B2) / den3;
        float s2n = an * an * dcc + 2.0f * an * bn * cw + bn * bn * sw;
        float nn = sqrtf(fmaxf(s2n, EPSF));
        float pj2 = (nn > MAXNF) ? (MAXNF / nn) : 1.0f;
        ans[row] = an * pj2;
        bns[row] = bn * pj2;
    }
    __syncthreads();

    // store out0 from C-layout (4 rows x 64B per instr, coalesced)
    float* ob = out + (size_t)r0 * DDIM + w * 64 + l15;
#pragma unroll
    for (int m = 0; m < 4; ++m) {
        int rbase = m * 16 + quad * 4;
        float anv[4], bnv[4];
#pragma unroll
        for (int r = 0; r < 4; ++r) { anv[r] = ans[rbase + r]; bnv[r] = bns[rbase + r]; }
#pragma unroll
        for (int j = 0; j < 4; ++j) {
#pragma unroll
            for (int r = 0; r < 4; ++r) {
                float xv = xb[(size_t)(rbase + r) * DDIM + j * 16];
                ob[(size_t)(rbase + r) * DDIM + j * 16] = fmaf(anv[r], xv, bnv[r] * acc[m][j][r]);
            }
        }
    }
}

extern "C" void kernel_launch(void* const* d_in, const int* in_sizes, int n_in,
                              void* d_out, int out_size, void* d_ws, size_t ws_size,
                              hipStream_t stream) {
    const float* xc = (const float*)d_in[0];
    const float* xp = (const float*)d_in[1];
    const float* z = (const float*)d_in[2];
    const float* bias = (const float*)d_in[3];
    const float* alpha = (const float*)d_in[4];
    const float* stepsz = (const float*)d_in[5];
    float* out = (float*)d_out;

    float* znf = (float*)d_ws;            // 512 f32
    float* chv = znf + 512;               // 512 f32
    float* shv = znf + 1024;              // 512 f32
    unsigned short* zT = (unsigned short*)(znf + 1536);  // 512x512 bf16 (transposed z_unit)

    prep_kernel<<<512, 64, 0, stream>>>(z, bias, znf, chv, shv, zT);
    hpd_main<<<BROWS / 64, 512, 0, stream>>>(xc, xp, znf, chv, shv, zT, alpha, stepsz, out);
}